// Round 11
// baseline (275.335 us; speedup 1.0000x reference)
//
#include <hip/hip_runtime.h>

// SelfAttention: out = softmax((xWq)(xWk)^T/32) @ (xWv), f32, S=4096, D=1024.
// R11: k_qkt reshaped to 256x128 tile / 512 blocks = 2 blocks/CU (cross-block
// TLP hides barrier stalls), LDS 2x40KiB = exactly 160KiB/CU, lb(512,4).
// Structure: scores = 8rr^T + (pr^T+rq^T)/64 + (x·(Mres/32))·x^T.
// ws (MiB): xh 0, xl 8 (r/p/q overlay), Th 16, Tl 24, Vt 32, S 40..104;
//   P 0..32 after softmax; temps in dead-S: Wqh 40.., Mth 48, Mtl 50,
//   Wtvh 52, sa/sb 54.

typedef _Float16 f16;
typedef f16 f16x8 __attribute__((ext_vector_type(8)));
typedef f16 f16x4v __attribute__((ext_vector_type(4)));
typedef float f32x4 __attribute__((ext_vector_type(4)));
typedef float f32x16 __attribute__((ext_vector_type(16)));
typedef unsigned short u16;
typedef u16 u16x8 __attribute__((ext_vector_type(8)));

extern __shared__ char dsm[];  // single dynamic-LDS symbol for the whole TU

__device__ __forceinline__ void split_f32(float v, f16& h, f16& l) {
  h = (f16)v;
  l = (f16)(v - (float)h);
}

__device__ __forceinline__ void gload16(const void* g, void* l) {
  __builtin_amdgcn_global_load_lds(
      (const __attribute__((address_space(1))) void*)g,
      (__attribute__((address_space(3))) void*)l, 16, 0, 0);
}

// ---- prep: elementwise split f32 -> (h,l) f16 for x, Wq, Wk ----
__global__ __launch_bounds__(256) void k_split(
    const float* __restrict__ x, const float* __restrict__ wq,
    const float* __restrict__ wk, f16* __restrict__ xh, f16* __restrict__ xl,
    f16* __restrict__ qh, f16* __restrict__ ql, f16* __restrict__ kh,
    f16* __restrict__ kl) {
  const int z = blockIdx.z;
  const float* __restrict__ src = (z == 0) ? x : (z == 1) ? wq : wk;
  f16* __restrict__ oh = (z == 0) ? xh : (z == 1) ? qh : kh;
  f16* __restrict__ ol = (z == 0) ? xl : (z == 1) ? ql : kl;
  const int n4 = (z == 0) ? (4096 * 1024 / 4) : (1024 * 1024 / 4);
  for (int i = blockIdx.x * 256 + threadIdx.x; i < n4; i += 1024 * 256) {
    float4 f = ((const float4*)src)[i];
    f16x4v h, l;
    f16 hh, ll;
    split_f32(f.x, hh, ll); h[0] = hh; l[0] = ll;
    split_f32(f.y, hh, ll); h[1] = hh; l[1] = ll;
    split_f32(f.z, hh, ll); h[2] = hh; l[2] = ll;
    split_f32(f.w, hh, ll); h[3] = hh; l[3] = ll;
    ((f16x4v*)oh)[i] = h;
    ((f16x4v*)ol)[i] = l;
  }
}

// ---- prep: transpose+split-h Wv [a][d] f32 -> Wtvh [d][a] f16 ----
__global__ __launch_bounds__(256) void k_wsplit_v(const float* __restrict__ Wv,
                                                  f16* __restrict__ vt) {
  __shared__ float sh[64][65];
  const int kb = blockIdx.x * 64, nb = blockIdx.y * 64;
  const int t = threadIdx.x;
  const int r = t >> 2, c4 = (t & 3) * 16;
#pragma unroll
  for (int i = 0; i < 4; ++i) {
    float4 f = *(const float4*)&Wv[(size_t)(kb + r) * 1024 + nb + c4 + i * 4];
    sh[r][c4 + i * 4 + 0] = f.x;
    sh[r][c4 + i * 4 + 1] = f.y;
    sh[r][c4 + i * 4 + 2] = f.z;
    sh[r][c4 + i * 4 + 3] = f.w;
  }
  __syncthreads();
  const int n = t >> 2, ks = (t & 3) * 16;
  u16x8 h0, h1;
#pragma unroll
  for (int i = 0; i < 8; ++i) {
    h0[i] = __builtin_bit_cast(u16, (f16)sh[ks + i][n]);
    h1[i] = __builtin_bit_cast(u16, (f16)sh[ks + 8 + i][n]);
  }
  const size_t o = (size_t)(nb + n) * 1024 + kb + ks;
  *(u16x8*)&vt[o] = h0;
  *(u16x8*)&vt[o + 8] = h1;
}

// ---- prep: centered row sums ----
__global__ __launch_bounds__(256) void k_rowsums(const float* __restrict__ Wq,
                                                 const float* __restrict__ Wk,
                                                 float* __restrict__ sa,
                                                 float* __restrict__ sb) {
  const int z = blockIdx.y;
  const float* __restrict__ W = z ? Wk : Wq;
  float* __restrict__ o = z ? sb : sa;
  const int row = blockIdx.x * 4 + (threadIdx.x >> 6);
  const int lane = threadIdx.x & 63;
  const float4* src = (const float4*)(W + (size_t)row * 1024);
  float s = 0.f;
#pragma unroll
  for (int i = 0; i < 4; ++i) {
    float4 f = src[lane + 64 * i];
    s += f.x + f.y + f.z + f.w;
  }
#pragma unroll
  for (int off = 1; off < 64; off <<= 1) s += __shfl_xor(s, off, 64);
  if (lane == 0) o[row] = s - 512.0f;
}

// ---- prep: r = x*1, p = x*sa, q = x*sb ----
__global__ __launch_bounds__(256) void k_rpq(
    const float* __restrict__ x, const float* __restrict__ sa,
    const float* __restrict__ sb, float* __restrict__ rv,
    float* __restrict__ pv, float* __restrict__ qv) {
  const int row = blockIdx.x * 4 + (threadIdx.x >> 6);
  const int lane = threadIdx.x & 63;
  const float* xr = x + (size_t)row * 1024;
  float sr = 0.f, sp = 0.f, sq = 0.f;
#pragma unroll
  for (int i = 0; i < 4; ++i) {
    const int c = (lane + 64 * i) * 4;
    float4 f = *(const float4*)&xr[c];
    float4 a = *(const float4*)&sa[c];
    float4 b = *(const float4*)&sb[c];
    sr += f.x + f.y + f.z + f.w;
    sp += f.x * a.x + f.y * a.y + f.z * a.z + f.w * a.w;
    sq += f.x * b.x + f.y * b.y + f.z * b.z + f.w * b.w;
  }
#pragma unroll
  for (int off = 1; off < 64; off <<= 1) {
    sr += __shfl_xor(sr, off, 64);
    sp += __shfl_xor(sp, off, 64);
    sq += __shfl_xor(sq, off, 64);
  }
  if (lane == 0) {
    rv[row] = sr;
    pv[row] = sp;
    qv[row] = sq;
  }
}

// ---- S-residual: S = T*xh^T + rank1; 256x128 tile, 2 blocks/CU ----
// LDS buffer (40 KiB): Ah[0,16K) Al[16K,32K) Bx[32K,40K). Rows of 64 B;
// 16B-slot swizzle: slot ^= (row>>1)&3 (global src + ds_read).
__global__ __launch_bounds__(512, 4) void k_qkt(
    const f16* __restrict__ Ah, const f16* __restrict__ Al,
    const f16* __restrict__ Bx, const float* __restrict__ rv,
    const float* __restrict__ pv, const float* __restrict__ qv,
    float* __restrict__ S) {
  char* smem = dsm;
  constexpr int K = 1024, N = 4096, nT = 32, BUF = 40960;
  const int tid = threadIdx.x;
  const int lane = tid & 63, wv = tid >> 6;
  const int wm = wv >> 2, wn = wv & 3;  // 2x4 waves, each 128x32
  const int bid = blockIdx.x;           // 512 blocks
  const int wg = (bid & 7) * 64 + (bid >> 3);  // bijective XCD swizzle
  const int bx = wg >> 5, by = wg & 31;        // 16 x 32
  const int brow = bx * 256, bcol = by * 128;

  const int srow16 = lane >> 2;
  const int sslot = (lane & 3) ^ ((lane >> 3) & 3);

  // 40 groups of 1 KiB: g 0..15 Ah, 16..31 Al, 32..39 Bx; wave owns g=wv*5+j
  auto stage = [&](int buf, int t) {
    const int kt = t * 32;
    char* bb = smem + BUF * buf;
#pragma unroll
    for (int j = 0; j < 5; ++j) {
      const int g = wv * 5 + j;
      const f16* gb;
      int grow;
      if (g < 16) {
        gb = Ah; grow = brow + g * 16;
      } else if (g < 32) {
        gb = Al; grow = brow + (g - 16) * 16;
      } else {
        gb = Bx; grow = bcol + (g - 32) * 16;
      }
      gload16(gb + (size_t)(grow + srow16) * K + kt + 8 * sslot, bb + g * 1024);
    }
  };

  f32x16 acc[4] = {};
  const int l31 = lane & 31, ch0 = lane >> 5;
  const int arow0 = wm * 128 + l31;  // + fm*32
  const int brow0 = wn * 32 + l31;

  stage(0, 0);

  for (int t = 0; t < nT; ++t) {
    const int cur = t & 1;
    const char* bb = smem + BUF * cur;
    if (t < nT - 1) {
      stage(cur ^ 1, t + 1);
      __builtin_amdgcn_sched_barrier(0);
      asm volatile("s_waitcnt vmcnt(5)" ::: "memory");  // tile t landed (mine)
    } else {
      asm volatile("s_waitcnt vmcnt(0)" ::: "memory");
    }
    __builtin_amdgcn_sched_barrier(0);
    __builtin_amdgcn_s_barrier();  // everyone's tile-t staging landed
    __builtin_amdgcn_sched_barrier(0);
#pragma unroll
    for (int ks = 0; ks < 2; ++ks) {
      const int ch = ks * 2 + ch0;
      f16x8 a_h[4], a_l[4], b_h;
#pragma unroll
      for (int fm = 0; fm < 4; ++fm) {
        const int r = arow0 + fm * 32;
        const int off = r * 64 + 16 * (ch ^ ((r >> 1) & 3));
        a_h[fm] = *(const f16x8*)(bb + off);
        a_l[fm] = *(const f16x8*)(bb + 16384 + off);
      }
      b_h = *(const f16x8*)(bb + 32768 + brow0 * 64 +
                            16 * (ch ^ ((brow0 >> 1) & 3)));
      __builtin_amdgcn_sched_barrier(0);
      asm volatile("s_waitcnt lgkmcnt(0)" ::: "memory");
      __builtin_amdgcn_sched_barrier(0);
      __builtin_amdgcn_s_setprio(1);
#pragma unroll
      for (int fm = 0; fm < 4; ++fm) {
        acc[fm] = __builtin_amdgcn_mfma_f32_32x32x16_f16(a_h[fm], b_h, acc[fm],
                                                         0, 0, 0);
        acc[fm] = __builtin_amdgcn_mfma_f32_32x32x16_f16(a_l[fm], b_h, acc[fm],
                                                         0, 0, 0);
      }
      __builtin_amdgcn_s_setprio(0);
      __builtin_amdgcn_sched_barrier(0);
    }
    __builtin_amdgcn_s_barrier();  // all reads of buf cur drained (WAR)
  }

  // epilogue: add rank-1 terms 8*r_i*r_j + (p_i*r_j + r_i*q_j)/64
  const int col = bcol + wn * 32 + l31;
  const float rc = rv[col], qc = qv[col];
#pragma unroll
  for (int fm = 0; fm < 4; ++fm)
#pragma unroll
    for (int j = 0; j < 16; ++j) {
      const int row =
          brow + wm * 128 + fm * 32 + (j & 3) + 8 * (j >> 2) + 4 * ch0;
      const float rr = rv[row];
      S[(size_t)row * N + col] =
          acc[fm][j] + 8.0f * rr * rc + (pv[row] * rc + rr * qc) * 0.015625f;
    }
}

// ---- P·V: out = P[4096][4096] · Vt[1024][4096]^T, depth-3 pipeline ----
__global__ __launch_bounds__(512, 1) void k_pv(const f16* __restrict__ P,
                                               const f16* __restrict__ Vt,
                                               float* __restrict__ out) {
  char* smem = dsm;
  constexpr int K = 4096, nT = K / 32, BUF = 16384;
  const int tid = threadIdx.x;
  const int lane = tid & 63, wv = tid >> 6;
  const int wm = wv >> 2, wn = wv & 3;
  const int bid = blockIdx.x;                  // 256 blocks
  const int wg = (bid & 7) * 32 + (bid >> 3);  // bijective XCD swizzle
  const int bx = wg >> 3, by = wg & 7;         // 32 x 8
  const int brow = bx * 128, bcol = by * 128;

  const int srow16 = lane >> 2;
  const int sslot = (lane & 3) ^ ((lane >> 3) & 3);
  const int sreg = wv >> 2;  // 0: A=P rows, 1: B=Vt rows
  const f16* __restrict__ sbase = sreg ? Vt : P;
  const int rbase = sreg ? bcol : brow;

  auto stage = [&](int buf, int t) {
    const int kt = t * 32;
    char* bb = smem + BUF * buf + sreg * 8192;
#pragma unroll
    for (int j = 0; j < 2; ++j) {
      const int g = (wv & 3) * 2 + j;
      gload16(sbase + (size_t)(rbase + g * 16 + srow16) * K + kt + 8 * sslot,
              bb + g * 1024);
    }
  };

  f32x16 acc[2] = {};
  const int l31 = lane & 31, ch0 = lane >> 5;
  const int arow0 = wm * 64 + l31;
  const int brow0 = wn * 32 + l31;

  stage(0, 0);
  stage(1, 1);
  stage(2, 2);

  for (int t = 0; t < nT; ++t) {
    const int rem = nT - 1 - t;
    if (rem >= 3) stage((t + 3) & 3, t + 3);
    __builtin_amdgcn_sched_barrier(0);
    if (rem >= 3) {
      asm volatile("s_waitcnt vmcnt(6)" ::: "memory");
    } else if (rem == 2) {
      asm volatile("s_waitcnt vmcnt(4)" ::: "memory");
    } else if (rem == 1) {
      asm volatile("s_waitcnt vmcnt(2)" ::: "memory");
    } else {
      asm volatile("s_waitcnt vmcnt(0)" ::: "memory");
    }
    __builtin_amdgcn_sched_barrier(0);
    __builtin_amdgcn_s_barrier();
    __builtin_amdgcn_sched_barrier(0);
    const char* bb = smem + BUF * (t & 3);
#pragma unroll
    for (int ks = 0; ks < 2; ++ks) {
      const int ch = ks * 2 + ch0;
      f16x8 a_h[2], b_h;
#pragma unroll
      for (int fm = 0; fm < 2; ++fm) {
        const int r = arow0 + fm * 32;
        a_h[fm] = *(const f16x8*)(bb + r * 64 + 16 * (ch ^ ((r >> 1) & 3)));
      }
      b_h = *(const f16x8*)(bb + 8192 + brow0 * 64 +
                            16 * (ch ^ ((brow0 >> 1) & 3)));
      __builtin_amdgcn_sched_barrier(0);
      asm volatile("s_waitcnt lgkmcnt(0)" ::: "memory");
      __builtin_amdgcn_sched_barrier(0);
      __builtin_amdgcn_s_setprio(1);
#pragma unroll
      for (int fm = 0; fm < 2; ++fm)
        acc[fm] = __builtin_amdgcn_mfma_f32_32x32x16_f16(a_h[fm], b_h, acc[fm],
                                                         0, 0, 0);
      __builtin_amdgcn_s_setprio(0);
      __builtin_amdgcn_sched_barrier(0);
    }
    __builtin_amdgcn_s_barrier();
  }

#pragma unroll
  for (int fm = 0; fm < 2; ++fm) {
    const int col = bcol + wn * 32 + l31;
#pragma unroll
    for (int j = 0; j < 16; ++j) {
      const int row =
          brow + wm * 64 + fm * 32 + (j & 3) + 8 * (j >> 2) + 4 * ch0;
      out[(size_t)row * 1024 + col] = acc[fm][j];
    }
  }
}

// ---- generic BT-GEMM (m97-style) ----
// OUT: 1 split f16; 2 f16; 3 rank1-subtract then split f16.
template <int NM, int OUT>
__global__ __launch_bounds__(256) void gemm_bt(
    const f16* __restrict__ A, const f16* __restrict__ Al,
    const f16* __restrict__ B, const f16* __restrict__ Bl, int K,
    float* __restrict__ outf, f16* __restrict__ oh, f16* __restrict__ ol,
    int ldo, float scale, const float* __restrict__ sav,
    const float* __restrict__ sbv) {
  f16* smem = (f16*)dsm;
  f16* tAh = smem;
  f16* tBh = smem + 8192;
  f16* tAl = smem + 16384;
  f16* tBl = smem + 24576;

  const int tid = threadIdx.x;
  const int lane = tid & 63, wid = tid >> 6;
  const int wr = wid >> 1, wc = wid & 1;
  const int brow = blockIdx.x * 128, bcol = blockIdx.y * 128;
  const int ar = lane & 15, k0 = (lane >> 4) * 8;
  const int crow = lane >> 3, ccol = (lane & 7) * 8;

  f32x4 acc[4][4] = {};
  const size_t aoff = (size_t)crow * K + ccol;

  for (int kt = 0; kt < K; kt += 64) {
    const f16* Ab = A + (size_t)brow * K + kt;
    const f16* Bb = B + (size_t)bcol * K + kt;
#pragma unroll
    for (int cc = 0; cc < 4; ++cc) {
      const int c = wid * 4 + cc;
      const size_t co = (size_t)c * 8 * K + aoff;
      gload16(Ab + co, tAh + c * 512);
      gload16(Bb + co, tBh + c * 512);
      if constexpr (NM == 3) {
        gload16(Al + (size_t)brow * K + kt + co, tAl + c * 512);
        gload16(Bl + (size_t)bcol * K + kt + co, tBl + c * 512);
      }
    }
    __syncthreads();
#pragma unroll
    for (int ks = 0; ks < 2; ++ks) {
      f16x8 ah[4], bh[4], alv[4], blv[4];
#pragma unroll
      for (int m = 0; m < 4; ++m) {
        ah[m] = *(const f16x8*)&tAh[(wr * 64 + m * 16 + ar) * 64 + ks * 32 + k0];
        bh[m] = *(const f16x8*)&tBh[(wc * 64 + m * 16 + ar) * 64 + ks * 32 + k0];
        if constexpr (NM == 3) {
          alv[m] = *(const f16x8*)&tAl[(wr * 64 + m * 16 + ar) * 64 + ks * 32 + k0];
          blv[m] = *(const f16x8*)&tBl[(wc * 64 + m * 16 + ar) * 64 + ks * 32 + k0];
        }
      }
#pragma unroll
      for (int m = 0; m < 4; ++m)
#pragma unroll
        for (int n = 0; n < 4; ++n) {
          acc[m][n] = __builtin_amdgcn_mfma_f32_16x16x32_f16(ah[m], bh[n], acc[m][n], 0, 0, 0);
          if constexpr (NM == 3) {
            acc[m][n] = __builtin_amdgcn_mfma_f32_16x16x32_f16(ah[m], blv[n], acc[m][n], 0, 0, 0);
            acc[m][n] = __builtin_amdgcn_mfma_f32_16x16x32_f16(alv[m], bh[n], acc[m][n], 0, 0, 0);
          }
        }
    }
    __syncthreads();
  }

#pragma unroll
  for (int m = 0; m < 4; ++m)
#pragma unroll
    for (int n = 0; n < 4; ++n)
#pragma unroll
      for (int j = 0; j < 4; ++j) {
        const int row = brow + wr * 64 + m * 16 + (lane >> 4) * 4 + j;
        const int col = bcol + wc * 64 + n * 16 + ar;
        const size_t idx = (size_t)row * ldo + col;
        if constexpr (OUT == 1) {
          f16 h, l;
          split_f32(acc[m][n][j] * scale, h, l);
          oh[idx] = h;
          ol[idx] = l;
        } else if constexpr (OUT == 2) {
          oh[idx] = (f16)(acc[m][n][j] * scale);
        } else {
          const float v =
              (acc[m][n][j] - 256.0f - 0.5f * sav[col] - 0.5f * sbv[row]) * scale;
          f16 h, l;
          split_f32(v, h, l);
          oh[idx] = h;
          ol[idx] = l;
        }
      }
}

// ---- row softmax: S f32 [4096][4096] -> P f16 ----
__global__ __launch_bounds__(256) void k_softmax(const float* __restrict__ S,
                                                 f16* __restrict__ P) {
  const int row = blockIdx.x;
  const int tid = threadIdx.x;
  const int lane = tid & 63, wid = tid >> 6;
  const float* s = S + (size_t)row * 4096;
  float4 v[4];
#pragma unroll
  for (int i = 0; i < 4; ++i) v[i] = ((const float4*)s)[tid + 256 * i];

  float mx = -3.4e38f;
#pragma unroll
  for (int i = 0; i < 4; ++i)
    mx = fmaxf(mx, fmaxf(fmaxf(v[i].x, v[i].y), fmaxf(v[i].z, v[i].w)));
#pragma unroll
  for (int off = 1; off < 64; off <<= 1) mx = fmaxf(mx, __shfl_xor(mx, off, 64));
  __shared__ float red[4];
  if (lane == 0) red[wid] = mx;
  __syncthreads();
  mx = fmaxf(fmaxf(red[0], red[1]), fmaxf(red[2], red[3]));

  float sum = 0.f;
#pragma unroll
  for (int i = 0; i < 4; ++i) {
    v[i].x = __expf(v[i].x - mx); v[i].y = __expf(v[i].y - mx);
    v[i].z = __expf(v[i].z - mx); v[i].w = __expf(v[i].w - mx);
    sum += v[i].x + v[i].y + v[i].z + v[i].w;
  }
#pragma unroll
  for (int off = 1; off < 64; off <<= 1) sum += __shfl_xor(sum, off, 64);
  __syncthreads();
  if (lane == 0) red[wid] = sum;
  __syncthreads();
  sum = red[0] + red[1] + red[2] + red[3];
  const float inv = 1.0f / sum;

  f16* p = P + (size_t)row * 4096;
#pragma unroll
  for (int i = 0; i < 4; ++i) {
    f16x4v pv;
    pv[0] = (f16)(v[i].x * inv); pv[1] = (f16)(v[i].y * inv);
    pv[2] = (f16)(v[i].z * inv); pv[3] = (f16)(v[i].w * inv);
    ((f16x4v*)p)[tid + 256 * i] = pv;
  }
}

extern "C" void kernel_launch(void* const* d_in, const int* in_sizes, int n_in,
                              void* d_out, int out_size, void* d_ws,
                              size_t ws_size, hipStream_t stream) {
  const float* x = (const float*)d_in[0];
  const float* Wq = (const float*)d_in[1];
  const float* Wk = (const float*)d_in[2];
  const float* Wv = (const float*)d_in[3];
  float* out = (float*)d_out;
  char* ws = (char*)d_ws;
  const size_t MiB = 1u << 20;
  f16* xh = (f16*)(ws + 0 * MiB);
  f16* xl = (f16*)(ws + 8 * MiB);
  f16* Th = (f16*)(ws + 16 * MiB);
  f16* Tl = (f16*)(ws + 24 * MiB);
  f16* Vt = (f16*)(ws + 32 * MiB);
  float* S = (float*)(ws + 40 * MiB);
  f16* Pm = (f16*)(ws + 0 * MiB);
  f16* Wqh = (f16*)(ws + 40 * MiB);
  f16* Wql = (f16*)(ws + 42 * MiB);
  f16* Wkh = (f16*)(ws + 44 * MiB);
  f16* Wkl = (f16*)(ws + 46 * MiB);
  f16* Mth = (f16*)(ws + 48 * MiB);
  f16* Mtl = (f16*)(ws + 50 * MiB);
  f16* Wtvh = (f16*)(ws + 52 * MiB);
  float* sa = (float*)(ws + 54 * MiB);
  float* sb = (float*)(ws + 54 * MiB + 65536);
  float* rv = (float*)(ws + 8 * MiB);
  float* pv = (float*)(ws + 8 * MiB + 65536);
  float* qv = (float*)(ws + 8 * MiB + 131072);

  (void)hipFuncSetAttribute((const void*)k_qkt,
                            hipFuncAttributeMaxDynamicSharedMemorySize, 81920);
  (void)hipFuncSetAttribute((const void*)k_pv,
                            hipFuncAttributeMaxDynamicSharedMemorySize, 65536);

  k_split<<<dim3(1024, 1, 3), 256, 0, stream>>>(x, Wq, Wk, xh, xl, Wqh, Wql,
                                                Wkh, Wkl);
  k_wsplit_v<<<dim3(16, 16), 256, 0, stream>>>(Wv, Wtvh);
  k_rowsums<<<dim3(256, 2), 256, 0, stream>>>(Wq, Wk, sa, sb);
  gemm_bt<3, 3><<<dim3(8, 8), 256, 65536, stream>>>(
      Wkh, Wkl, Wqh, Wql, 1024, nullptr, Mth, Mtl, 1024, 0.03125f, sa, sb);
  gemm_bt<3, 1><<<dim3(32, 8), 256, 65536, stream>>>(
      xh, xl, Mth, Mtl, 1024, nullptr, Th, Tl, 1024, 1.0f, nullptr, nullptr);
  gemm_bt<1, 2><<<dim3(8, 32), 256, 32768, stream>>>(
      Wtvh, nullptr, xh, nullptr, 1024, nullptr, Vt, nullptr, 4096, 1.0f,
      nullptr, nullptr);
  k_rpq<<<dim3(1024), 256, 0, stream>>>(x, sa, sb, rv, pv, qv);
  k_qkt<<<dim3(512), 512, 81920, stream>>>(Th, Tl, xh, rv, pv, qv, S);
  k_softmax<<<dim3(4096), 256, 0, stream>>>(S, Pm);
  k_pv<<<dim3(256), 512, 65536, stream>>>(Pm, Vt, out);
}

// Round 12
// 249.100 us; speedup vs baseline: 1.1053x; 1.1053x over previous
//
#include <hip/hip_runtime.h>

// SelfAttention: out = softmax((xWq)(xWk)^T/32) @ (xWv), f32, S=4096, D=1024.
// R12: revert k_qkt to R10 (best: 76.7us); T-GEMM drops the xh*Mtl term
// (NM=2, Mt stored h-only; +~0.02 rms score err, in budget); Vt GEMM moved to
// the depth-3 pipelined structure (shared pipe_bt template with PV).
// scores = 8rr^T + (pr^T+rq^T)/64 + (x·(Mres/32))·x^T.
// ws (MiB): xh 0, xl 8 (r/p/q overlay), Th 16, Tl 24, Vt 32, S 40..104;
//   P 0..32 after softmax; temps in dead-S: Wqh 40.., Mth 48, Wtvh 52, sa/sb 54.

typedef _Float16 f16;
typedef f16 f16x8 __attribute__((ext_vector_type(8)));
typedef f16 f16x4v __attribute__((ext_vector_type(4)));
typedef float f32x4 __attribute__((ext_vector_type(4)));
typedef float f32x16 __attribute__((ext_vector_type(16)));
typedef unsigned short u16;
typedef u16 u16x8 __attribute__((ext_vector_type(8)));

extern __shared__ char dsm[];  // single dynamic-LDS symbol for the whole TU

__device__ __forceinline__ void split_f32(float v, f16& h, f16& l) {
  h = (f16)v;
  l = (f16)(v - (float)h);
}

__device__ __forceinline__ void gload16(const void* g, void* l) {
  __builtin_amdgcn_global_load_lds(
      (const __attribute__((address_space(1))) void*)g,
      (__attribute__((address_space(3))) void*)l, 16, 0, 0);
}

// ---- prep: elementwise split f32 -> (h,l) f16 for x, Wq, Wk ----
__global__ __launch_bounds__(256) void k_split(
    const float* __restrict__ x, const float* __restrict__ wq,
    const float* __restrict__ wk, f16* __restrict__ xh, f16* __restrict__ xl,
    f16* __restrict__ qh, f16* __restrict__ ql, f16* __restrict__ kh,
    f16* __restrict__ kl) {
  const int z = blockIdx.z;
  const float* __restrict__ src = (z == 0) ? x : (z == 1) ? wq : wk;
  f16* __restrict__ oh = (z == 0) ? xh : (z == 1) ? qh : kh;
  f16* __restrict__ ol = (z == 0) ? xl : (z == 1) ? ql : kl;
  const int n4 = (z == 0) ? (4096 * 1024 / 4) : (1024 * 1024 / 4);
  for (int i = blockIdx.x * 256 + threadIdx.x; i < n4; i += 1024 * 256) {
    float4 f = ((const float4*)src)[i];
    f16x4v h, l;
    f16 hh, ll;
    split_f32(f.x, hh, ll); h[0] = hh; l[0] = ll;
    split_f32(f.y, hh, ll); h[1] = hh; l[1] = ll;
    split_f32(f.z, hh, ll); h[2] = hh; l[2] = ll;
    split_f32(f.w, hh, ll); h[3] = hh; l[3] = ll;
    ((f16x4v*)oh)[i] = h;
    ((f16x4v*)ol)[i] = l;
  }
}

// ---- prep: transpose+split-h Wv [a][d] f32 -> Wtvh [d][a] f16 ----
__global__ __launch_bounds__(256) void k_wsplit_v(const float* __restrict__ Wv,
                                                  f16* __restrict__ vt) {
  __shared__ float sh[64][65];
  const int kb = blockIdx.x * 64, nb = blockIdx.y * 64;
  const int t = threadIdx.x;
  const int r = t >> 2, c4 = (t & 3) * 16;
#pragma unroll
  for (int i = 0; i < 4; ++i) {
    float4 f = *(const float4*)&Wv[(size_t)(kb + r) * 1024 + nb + c4 + i * 4];
    sh[r][c4 + i * 4 + 0] = f.x;
    sh[r][c4 + i * 4 + 1] = f.y;
    sh[r][c4 + i * 4 + 2] = f.z;
    sh[r][c4 + i * 4 + 3] = f.w;
  }
  __syncthreads();
  const int n = t >> 2, ks = (t & 3) * 16;
  u16x8 h0, h1;
#pragma unroll
  for (int i = 0; i < 8; ++i) {
    h0[i] = __builtin_bit_cast(u16, (f16)sh[ks + i][n]);
    h1[i] = __builtin_bit_cast(u16, (f16)sh[ks + 8 + i][n]);
  }
  const size_t o = (size_t)(nb + n) * 1024 + kb + ks;
  *(u16x8*)&vt[o] = h0;
  *(u16x8*)&vt[o + 8] = h1;
}

// ---- prep: centered row sums ----
__global__ __launch_bounds__(256) void k_rowsums(const float* __restrict__ Wq,
                                                 const float* __restrict__ Wk,
                                                 float* __restrict__ sa,
                                                 float* __restrict__ sb) {
  const int z = blockIdx.y;
  const float* __restrict__ W = z ? Wk : Wq;
  float* __restrict__ o = z ? sb : sa;
  const int row = blockIdx.x * 4 + (threadIdx.x >> 6);
  const int lane = threadIdx.x & 63;
  const float4* src = (const float4*)(W + (size_t)row * 1024);
  float s = 0.f;
#pragma unroll
  for (int i = 0; i < 4; ++i) {
    float4 f = src[lane + 64 * i];
    s += f.x + f.y + f.z + f.w;
  }
#pragma unroll
  for (int off = 1; off < 64; off <<= 1) s += __shfl_xor(s, off, 64);
  if (lane == 0) o[row] = s - 512.0f;
}

// ---- prep: r = x*1, p = x*sa, q = x*sb ----
__global__ __launch_bounds__(256) void k_rpq(
    const float* __restrict__ x, const float* __restrict__ sa,
    const float* __restrict__ sb, float* __restrict__ rv,
    float* __restrict__ pv, float* __restrict__ qv) {
  const int row = blockIdx.x * 4 + (threadIdx.x >> 6);
  const int lane = threadIdx.x & 63;
  const float* xr = x + (size_t)row * 1024;
  float sr = 0.f, sp = 0.f, sq = 0.f;
#pragma unroll
  for (int i = 0; i < 4; ++i) {
    const int c = (lane + 64 * i) * 4;
    float4 f = *(const float4*)&xr[c];
    float4 a = *(const float4*)&sa[c];
    float4 b = *(const float4*)&sb[c];
    sr += f.x + f.y + f.z + f.w;
    sp += f.x * a.x + f.y * a.y + f.z * a.z + f.w * a.w;
    sq += f.x * b.x + f.y * b.y + f.z * b.z + f.w * b.w;
  }
#pragma unroll
  for (int off = 1; off < 64; off <<= 1) {
    sr += __shfl_xor(sr, off, 64);
    sp += __shfl_xor(sp, off, 64);
    sq += __shfl_xor(sq, off, 64);
  }
  if (lane == 0) {
    rv[row] = sr;
    pv[row] = sp;
    qv[row] = sq;
  }
}

// ---- S-residual: S = T*xh^T + rank1, 256x256 tile, 2-buffer, 2-MFMA ----
// (R10 version — best measured.)  LDS buffer (48 KiB): Th Tl xh.
__global__ __launch_bounds__(512, 1) void k_qkt(
    const f16* __restrict__ Ah, const f16* __restrict__ Al,
    const f16* __restrict__ Bx, const float* __restrict__ rv,
    const float* __restrict__ pv, const float* __restrict__ qv,
    float* __restrict__ S) {
  char* smem = dsm;
  constexpr int K = 1024, N = 4096, nT = 32, BUF = 49152;
  const int tid = threadIdx.x;
  const int lane = tid & 63, wv = tid >> 6;
  const int wm = wv >> 2, wn = wv & 3;
  const int bid = blockIdx.x;
  const int wg = (bid & 7) * 32 + (bid >> 3);
  const int bx = wg >> 4, by = wg & 15;
  const int brow = bx * 256, bcol = by * 256;

  const int srow16 = lane >> 2;
  const int sslot = (lane & 3) ^ ((lane >> 3) & 3);

  const f16* bases[3] = {Ah, Al, Bx};
  const int rbase[3] = {brow, brow, bcol};

  auto stage3 = [&](int buf, int t, int half) {
    const int kt = t * 32;
    char* bb = smem + BUF * buf;
#pragma unroll
    for (int j = 0; j < 3; ++j) {
      const int g = wv * 6 + half * 3 + j;
      const int rg = g >> 4, gm = g & 15;
      gload16(
          bases[rg] + (size_t)(rbase[rg] + gm * 16 + srow16) * K + kt + 8 * sslot,
          bb + rg * 16384 + gm * 1024);
    }
  };

  f32x16 acc[4][2] = {};
  const int l31 = lane & 31, ch0 = lane >> 5;
  const int arow0 = wm * 128 + l31;
  const int brow0 = wn * 64 + l31;

  stage3(0, 0, 0);
  stage3(0, 0, 1);

  for (int t = 0; t < nT; ++t) {
    const int cur = t & 1;
    const char* bb = smem + BUF * cur;
    const bool pre = t < nT - 1;
    if (pre) {
      stage3(cur ^ 1, t + 1, 0);
      __builtin_amdgcn_sched_barrier(0);
      asm volatile("s_waitcnt vmcnt(3)" ::: "memory");
    } else {
      asm volatile("s_waitcnt vmcnt(0)" ::: "memory");
    }
    __builtin_amdgcn_sched_barrier(0);
    __builtin_amdgcn_s_barrier();
    __builtin_amdgcn_sched_barrier(0);
#pragma unroll
    for (int ks = 0; ks < 2; ++ks) {
      const int ch = ks * 2 + ch0;
      f16x8 a_h[4], a_l[4], b_h[2];
#pragma unroll
      for (int fm = 0; fm < 4; ++fm) {
        const int r = arow0 + fm * 32;
        const int off = r * 64 + 16 * (ch ^ ((r >> 1) & 3));
        a_h[fm] = *(const f16x8*)(bb + off);
        a_l[fm] = *(const f16x8*)(bb + 16384 + off);
      }
#pragma unroll
      for (int fn = 0; fn < 2; ++fn) {
        const int r = brow0 + fn * 32;
        const int off = r * 64 + 16 * (ch ^ ((r >> 1) & 3));
        b_h[fn] = *(const f16x8*)(bb + 32768 + off);
      }
      if (ks == 0 && pre) stage3(cur ^ 1, t + 1, 1);
      __builtin_amdgcn_sched_barrier(0);
      asm volatile("s_waitcnt lgkmcnt(0)" ::: "memory");
      __builtin_amdgcn_sched_barrier(0);
      __builtin_amdgcn_s_setprio(1);
#pragma unroll
      for (int fm = 0; fm < 4; ++fm)
#pragma unroll
        for (int fn = 0; fn < 2; ++fn) {
          acc[fm][fn] = __builtin_amdgcn_mfma_f32_32x32x16_f16(
              a_h[fm], b_h[fn], acc[fm][fn], 0, 0, 0);
          acc[fm][fn] = __builtin_amdgcn_mfma_f32_32x32x16_f16(
              a_l[fm], b_h[fn], acc[fm][fn], 0, 0, 0);
        }
      __builtin_amdgcn_s_setprio(0);
      __builtin_amdgcn_sched_barrier(0);
      __builtin_amdgcn_s_barrier();
    }
  }

#pragma unroll
  for (int fm = 0; fm < 4; ++fm)
#pragma unroll
    for (int fn = 0; fn < 2; ++fn) {
      const int col = bcol + wn * 64 + fn * 32 + l31;
      const float rc = rv[col], qc = qv[col];
#pragma unroll
      for (int j = 0; j < 16; ++j) {
        const int row =
            brow + wm * 128 + fm * 32 + (j & 3) + 8 * (j >> 2) + 4 * ch0;
        const float rr = rv[row];
        S[(size_t)row * N + col] =
            acc[fm][fn][j] + 8.0f * rr * rc + (pv[row] * rc + rr * qc) * 0.015625f;
      }
    }
}

// ---- depth-3 pipelined BT-GEMM: C[M][N] = A[M][K] . B[N][K]^T ----
// 128x128 tile, 512 thr (8 waves 2x4), 4 LDS bufs x 16KB.
// OUT=0: f32 out; OUT=2: f16 out. grid = (M/128)*(N/128) = 256 blocks.
template <int K, int NBY, int OUT>
__global__ __launch_bounds__(512, 1) void pipe_bt(const f16* __restrict__ A,
                                                  const f16* __restrict__ B,
                                                  float* __restrict__ outf,
                                                  f16* __restrict__ outh,
                                                  int ldo) {
  char* smem = dsm;
  constexpr int nT = K / 32, BUF = 16384;
  const int tid = threadIdx.x;
  const int lane = tid & 63, wv = tid >> 6;
  const int wm = wv >> 2, wn = wv & 3;
  const int bid = blockIdx.x;                  // 256 blocks
  const int wg = (bid & 7) * 32 + (bid >> 3);  // bijective XCD swizzle
  const int bx = wg / NBY, by = wg % NBY;
  const int brow = bx * 128, bcol = by * 128;

  const int srow16 = lane >> 2;
  const int sslot = (lane & 3) ^ ((lane >> 3) & 3);
  const int sreg = wv >> 2;  // 0: A rows, 1: B rows
  const f16* __restrict__ sbase = sreg ? B : A;
  const int rbase = sreg ? bcol : brow;

  auto stage = [&](int buf, int t) {
    const int kt = t * 32;
    char* bb = smem + BUF * buf + sreg * 8192;
#pragma unroll
    for (int j = 0; j < 2; ++j) {
      const int g = (wv & 3) * 2 + j;
      gload16(sbase + (size_t)(rbase + g * 16 + srow16) * K + kt + 8 * sslot,
              bb + g * 1024);
    }
  };

  f32x16 acc[2] = {};
  const int l31 = lane & 31, ch0 = lane >> 5;
  const int arow0 = wm * 64 + l31;
  const int brow0 = wn * 32 + l31;

  stage(0, 0);
  stage(1, 1);
  stage(2, 2);

  for (int t = 0; t < nT; ++t) {
    const int rem = nT - 1 - t;
    if (rem >= 3) stage((t + 3) & 3, t + 3);
    __builtin_amdgcn_sched_barrier(0);
    if (rem >= 3) {
      asm volatile("s_waitcnt vmcnt(6)" ::: "memory");
    } else if (rem == 2) {
      asm volatile("s_waitcnt vmcnt(4)" ::: "memory");
    } else if (rem == 1) {
      asm volatile("s_waitcnt vmcnt(2)" ::: "memory");
    } else {
      asm volatile("s_waitcnt vmcnt(0)" ::: "memory");
    }
    __builtin_amdgcn_sched_barrier(0);
    __builtin_amdgcn_s_barrier();
    __builtin_amdgcn_sched_barrier(0);
    const char* bb = smem + BUF * (t & 3);
#pragma unroll
    for (int ks = 0; ks < 2; ++ks) {
      const int ch = ks * 2 + ch0;
      f16x8 a_h[2], b_h;
#pragma unroll
      for (int fm = 0; fm < 2; ++fm) {
        const int r = arow0 + fm * 32;
        a_h[fm] = *(const f16x8*)(bb + r * 64 + 16 * (ch ^ ((r >> 1) & 3)));
      }
      b_h = *(const f16x8*)(bb + 8192 + brow0 * 64 +
                            16 * (ch ^ ((brow0 >> 1) & 3)));
      __builtin_amdgcn_sched_barrier(0);
      asm volatile("s_waitcnt lgkmcnt(0)" ::: "memory");
      __builtin_amdgcn_sched_barrier(0);
      __builtin_amdgcn_s_setprio(1);
#pragma unroll
      for (int fm = 0; fm < 2; ++fm)
        acc[fm] = __builtin_amdgcn_mfma_f32_32x32x16_f16(a_h[fm], b_h, acc[fm],
                                                         0, 0, 0);
      __builtin_amdgcn_s_setprio(0);
      __builtin_amdgcn_sched_barrier(0);
    }
    __builtin_amdgcn_s_barrier();
  }

#pragma unroll
  for (int fm = 0; fm < 2; ++fm) {
    const int col = bcol + wn * 32 + l31;
#pragma unroll
    for (int j = 0; j < 16; ++j) {
      const int row =
          brow + wm * 64 + fm * 32 + (j & 3) + 8 * (j >> 2) + 4 * ch0;
      if constexpr (OUT == 0) {
        outf[(size_t)row * ldo + col] = acc[fm][j];
      } else {
        outh[(size_t)row * ldo + col] = (f16)acc[fm][j];
      }
    }
  }
}

// ---- generic BT-GEMM (m97-style) ----
// NM: 3 = AhBh+AhBl+AlBh; 2 = AhBh+AlBh (no Bl).
// OUT: 1 split f16; 4 rank1-subtract then f16 h-only.
template <int NM, int OUT>
__global__ __launch_bounds__(256) void gemm_bt(
    const f16* __restrict__ A, const f16* __restrict__ Al,
    const f16* __restrict__ B, const f16* __restrict__ Bl, int K,
    f16* __restrict__ oh, f16* __restrict__ ol, int ldo, float scale,
    const float* __restrict__ sav, const float* __restrict__ sbv) {
  f16* smem = (f16*)dsm;
  f16* tAh = smem;
  f16* tBh = smem + 8192;
  f16* tAl = smem + 16384;
  f16* tBl = smem + 24576;

  const int tid = threadIdx.x;
  const int lane = tid & 63, wid = tid >> 6;
  const int wr = wid >> 1, wc = wid & 1;
  const int brow = blockIdx.x * 128, bcol = blockIdx.y * 128;
  const int ar = lane & 15, k0 = (lane >> 4) * 8;
  const int crow = lane >> 3, ccol = (lane & 7) * 8;

  f32x4 acc[4][4] = {};
  const size_t aoff = (size_t)crow * K + ccol;

  for (int kt = 0; kt < K; kt += 64) {
    const f16* Ab = A + (size_t)brow * K + kt;
    const f16* Bb = B + (size_t)bcol * K + kt;
#pragma unroll
    for (int cc = 0; cc < 4; ++cc) {
      const int c = wid * 4 + cc;
      const size_t co = (size_t)c * 8 * K + aoff;
      gload16(Ab + co, tAh + c * 512);
      gload16(Bb + co, tBh + c * 512);
      if constexpr (NM >= 2) gload16(Al + (size_t)brow * K + kt + co, tAl + c * 512);
      if constexpr (NM == 3) gload16(Bl + (size_t)bcol * K + kt + co, tBl + c * 512);
    }
    __syncthreads();
#pragma unroll
    for (int ks = 0; ks < 2; ++ks) {
      f16x8 ah[4], bh[4], alv[4], blv[4];
#pragma unroll
      for (int m = 0; m < 4; ++m) {
        ah[m] = *(const f16x8*)&tAh[(wr * 64 + m * 16 + ar) * 64 + ks * 32 + k0];
        bh[m] = *(const f16x8*)&tBh[(wc * 64 + m * 16 + ar) * 64 + ks * 32 + k0];
        if constexpr (NM >= 2)
          alv[m] = *(const f16x8*)&tAl[(wr * 64 + m * 16 + ar) * 64 + ks * 32 + k0];
        if constexpr (NM == 3)
          blv[m] = *(const f16x8*)&tBl[(wc * 64 + m * 16 + ar) * 64 + ks * 32 + k0];
      }
#pragma unroll
      for (int m = 0; m < 4; ++m)
#pragma unroll
        for (int n = 0; n < 4; ++n) {
          acc[m][n] = __builtin_amdgcn_mfma_f32_16x16x32_f16(ah[m], bh[n], acc[m][n], 0, 0, 0);
          if constexpr (NM >= 2)
            acc[m][n] = __builtin_amdgcn_mfma_f32_16x16x32_f16(alv[m], bh[n], acc[m][n], 0, 0, 0);
          if constexpr (NM == 3)
            acc[m][n] = __builtin_amdgcn_mfma_f32_16x16x32_f16(ah[m], blv[n], acc[m][n], 0, 0, 0);
        }
    }
    __syncthreads();
  }

#pragma unroll
  for (int m = 0; m < 4; ++m)
#pragma unroll
    for (int n = 0; n < 4; ++n)
#pragma unroll
      for (int j = 0; j < 4; ++j) {
        const int row = brow + wr * 64 + m * 16 + (lane >> 4) * 4 + j;
        const int col = bcol + wc * 64 + n * 16 + ar;
        const size_t idx = (size_t)row * ldo + col;
        if constexpr (OUT == 1) {
          f16 h, l;
          split_f32(acc[m][n][j] * scale, h, l);
          oh[idx] = h;
          ol[idx] = l;
        } else {  // OUT == 4: rank1-subtract, h only
          const float v =
              (acc[m][n][j] - 256.0f - 0.5f * sav[col] - 0.5f * sbv[row]) * scale;
          oh[idx] = (f16)v;
        }
      }
}

// ---- row softmax: S f32 [4096][4096] -> P f16 ----
__global__ __launch_bounds__(256) void k_softmax(const float* __restrict__ S,
                                                 f16* __restrict__ P) {
  const int row = blockIdx.x;
  const int tid = threadIdx.x;
  const int lane = tid & 63, wid = tid >> 6;
  const float* s = S + (size_t)row * 4096;
  float4 v[4];
#pragma unroll
  for (int i = 0; i < 4; ++i) v[i] = ((const float4*)s)[tid + 256 * i];

  float mx = -3.4e38f;
#pragma unroll
  for (int i = 0; i < 4; ++i)
    mx = fmaxf(mx, fmaxf(fmaxf(v[i].x, v[i].y), fmaxf(v[i].z, v[i].w)));
#pragma unroll
  for (int off = 1; off < 64; off <<= 1) mx = fmaxf(mx, __shfl_xor(mx, off, 64));
  __shared__ float red[4];
  if (lane == 0) red[wid] = mx;
  __syncthreads();
  mx = fmaxf(fmaxf(red[0], red[1]), fmaxf(red[2], red[3]));

  float sum = 0.f;
#pragma unroll
  for (int i = 0; i < 4; ++i) {
    v[i].x = __expf(v[i].x - mx); v[i].y = __expf(v[i].y - mx);
    v[i].z = __expf(v[i].z - mx); v[i].w = __expf(v[i].w - mx);
    sum += v[i].x + v[i].y + v[i].z + v[i].w;
  }
#pragma unroll
  for (int off = 1; off < 64; off <<= 1) sum += __shfl_xor(sum, off, 64);
  __syncthreads();
  if (lane == 0) red[wid] = sum;
  __syncthreads();
  sum = red[0] + red[1] + red[2] + red[3];
  const float inv = 1.0f / sum;

  f16* p = P + (size_t)row * 4096;
#pragma unroll
  for (int i = 0; i < 4; ++i) {
    f16x4v pv;
    pv[0] = (f16)(v[i].x * inv); pv[1] = (f16)(v[i].y * inv);
    pv[2] = (f16)(v[i].z * inv); pv[3] = (f16)(v[i].w * inv);
    ((f16x4v*)p)[tid + 256 * i] = pv;
  }
}

extern "C" void kernel_launch(void* const* d_in, const int* in_sizes, int n_in,
                              void* d_out, int out_size, void* d_ws,
                              size_t ws_size, hipStream_t stream) {
  const float* x = (const float*)d_in[0];
  const float* Wq = (const float*)d_in[1];
  const float* Wk = (const float*)d_in[2];
  const float* Wv = (const float*)d_in[3];
  float* out = (float*)d_out;
  char* ws = (char*)d_ws;
  const size_t MiB = 1u << 20;
  f16* xh = (f16*)(ws + 0 * MiB);
  f16* xl = (f16*)(ws + 8 * MiB);
  f16* Th = (f16*)(ws + 16 * MiB);
  f16* Tl = (f16*)(ws + 24 * MiB);
  f16* Vt = (f16*)(ws + 32 * MiB);
  float* S = (float*)(ws + 40 * MiB);
  f16* Pm = (f16*)(ws + 0 * MiB);
  f16* Wqh = (f16*)(ws + 40 * MiB);
  f16* Wql = (f16*)(ws + 42 * MiB);
  f16* Wkh = (f16*)(ws + 44 * MiB);
  f16* Wkl = (f16*)(ws + 46 * MiB);
  f16* Mth = (f16*)(ws + 48 * MiB);
  f16* Wtvh = (f16*)(ws + 52 * MiB);
  float* sa = (float*)(ws + 54 * MiB);
  float* sb = (float*)(ws + 54 * MiB + 65536);
  float* rv = (float*)(ws + 8 * MiB);
  float* pv = (float*)(ws + 8 * MiB + 65536);
  float* qv = (float*)(ws + 8 * MiB + 131072);

  (void)hipFuncSetAttribute((const void*)k_qkt,
                            hipFuncAttributeMaxDynamicSharedMemorySize, 98304);
  (void)hipFuncSetAttribute((const void*)pipe_bt<4096, 8, 0>,
                            hipFuncAttributeMaxDynamicSharedMemorySize, 65536);
  (void)hipFuncSetAttribute((const void*)pipe_bt<1024, 32, 2>,
                            hipFuncAttributeMaxDynamicSharedMemorySize, 65536);

  k_split<<<dim3(1024, 1, 3), 256, 0, stream>>>(x, Wq, Wk, xh, xl, Wqh, Wql,
                                                Wkh, Wkl);
  k_wsplit_v<<<dim3(16, 16), 256, 0, stream>>>(Wv, Wtvh);
  k_rowsums<<<dim3(256, 2), 256, 0, stream>>>(Wq, Wk, sa, sb);
  // Mres^T/32, rank1-subtracted, h-only (3-MFMA for precision of the product)
  gemm_bt<3, 4><<<dim3(8, 8), 256, 65536, stream>>>(
      Wkh, Wkl, Wqh, Wql, 1024, Mth, nullptr, 1024, 0.03125f, sa, sb);
  // T = x·(Mres/32): NM=2 (xh*Mth + xl*Mth), split f16 out
  gemm_bt<2, 1><<<dim3(32, 8), 256, 49152, stream>>>(
      xh, xl, Mth, nullptr, 1024, Th, Tl, 1024, 1.0f, nullptr, nullptr);
  // Vt = (x·Wv)^T via pipelined GEMM: A=Wtvh[1024][1024], B=xh[4096][1024]
  pipe_bt<1024, 32, 2><<<dim3(256), 512, 65536, stream>>>(Wtvh, xh, nullptr,
                                                          Vt, 4096);
  k_rpq<<<dim3(1024), 256, 0, stream>>>(x, sa, sb, rv, pv, qv);
  k_qkt<<<dim3(256), 512, 98304, stream>>>(Th, Tl, xh, rv, pv, qv, S);
  k_softmax<<<dim3(4096), 256, 0, stream>>>(S, Pm);
  // out = P·Vt^T via pipelined GEMM
  pipe_bt<4096, 8, 0><<<dim3(256), 512, 65536, stream>>>(Pm, Vt, out, nullptr,
                                                         1024);
}